// Round 5
// baseline (714.999 us; speedup 1.0000x reference)
//
#include <hip/hip_runtime.h>
#include <math.h>

// Problem dims (fixed)
#define BB   16
#define SS   2048
#define DIN  256
#define DEMB 512
#define DKQ  512
#define DVV  512

typedef _Float16 f16;
typedef _Float16 half8  __attribute__((ext_vector_type(8)));
typedef _Float16 f16x4  __attribute__((ext_vector_type(4)));
typedef float    f32x4  __attribute__((ext_vector_type(4)));
typedef float    f32x16 __attribute__((ext_vector_type(16)));

#define GLOAD_LDS16(gp, lp)                                                        \
  __builtin_amdgcn_global_load_lds(                                                \
      (const __attribute__((address_space(1))) unsigned int*)(gp),                 \
      (__attribute__((address_space(3))) unsigned int*)(lp), 16, 0, 0)

// ---------------------------------------------------------------------------
// Kernel 0: split x (fp32) -> Xh, Xl (fp16 pair, exact to ~2^-22)
// ---------------------------------------------------------------------------
__global__ __launch_bounds__(256) void prep_x(
    const float* __restrict__ x, f16* __restrict__ Xh, f16* __restrict__ Xl)
{
    int idx = blockIdx.x * 256 + threadIdx.x;
    float4 v = ((const float4*)x)[idx];
    f16x4 h, l;
    h.x = (f16)v.x; l.x = (f16)(v.x - (float)h.x);
    h.y = (f16)v.y; l.y = (f16)(v.y - (float)h.y);
    h.z = (f16)v.z; l.z = (f16)(v.z - (float)h.z);
    h.w = (f16)v.w; l.w = (f16)(v.w - (float)h.w);
    ((f16x4*)Xh)[idx] = h;
    ((f16x4*)Xl)[idx] = l;
}

// ---------------------------------------------------------------------------
// Kernel 1: fuse weights W' = W_embed @ W (fp32 math), output TRANSPOSED
// fp16 split:  Wth/Wtl [z][n=512][k=256]
// ---------------------------------------------------------------------------
__global__ __launch_bounds__(256) void fuse_weights(
    const float* __restrict__ We, const float* __restrict__ Wk,
    const float* __restrict__ Wq, const float* __restrict__ Wv,
    f16* __restrict__ Wth, f16* __restrict__ Wtl)
{
    int idx = blockIdx.x * 256 + threadIdx.x;
    int n = idx & 511;
    int m = (idx >> 9) & 255;
    int z = idx >> 17;
    const float* Wsrc = (z == 0) ? Wk : (z == 1) ? Wq : Wv;
    float sum = 0.f;
#pragma unroll 8
    for (int kk = 0; kk < DEMB; ++kk)
        sum += We[m * DEMB + kk] * Wsrc[kk * 512 + n];
    f16 h = (f16)sum;
    f16 l = (f16)(sum - (float)h);
    Wth[(size_t)z * 131072 + n * 256 + m] = h;
    Wtl[(size_t)z * 131072 + n * 256 + m] = l;
}

// ---------------------------------------------------------------------------
// Kernel 2: MFMA projections, 3-term fp16 split (Ah*Bh + Al*Bh + Ah*Bl).
// Tile 128x128, K-chunk 64, 4 waves. global_load_lds staging.
// Outputs:
//   z=0 -> Kf: MFMA A-fragment order [b][tile(64)][kb(2)][ks(16)][lane(64)][8]
//          (key=tile*32+kb*16+(lane&15), d=ks*32+(lane>>4)*8+j)
//   z=1 -> Qh row-major [row][512]
//   z=2 -> Vf: MFMA B-fragment order [b][tile(64)][nb(16)][ks(2)][lane(64)][8]
//          (dv=nb*32+(lane&31), key=tile*32+ks*16+(lane>>5)*8+j)
// ---------------------------------------------------------------------------
#define QAH 0
#define QAL 8192
#define QBH 16384
#define QBL 24576

__global__ __launch_bounds__(256) void qkv_gemm(
    const f16* __restrict__ Xh, const f16* __restrict__ Xl,
    const f16* __restrict__ Wth, const f16* __restrict__ Wtl,
    f16* __restrict__ Kf, f16* __restrict__ Qh, f16* __restrict__ Vf)
{
    __shared__ __align__(16) short smq[32768];   // 64 KB

    const int tid  = threadIdx.x;
    const int lane = tid & 63;
    const int w    = tid >> 6;
    const int z    = blockIdx.z;
    const int m0   = blockIdx.y * 128;
    const int n0   = blockIdx.x * 128;
    const int l15  = lane & 15;
    const int quad = lane >> 4;
    const int wm   = (w >> 1) * 64, wn = (w & 1) * 64;

    const f16* Bh = Wth + (size_t)z * 131072;
    const f16* Bl = Wtl + (size_t)z * 131072;

    f32x4 acc[4][4];
#pragma unroll
    for (int i = 0; i < 4; ++i)
#pragma unroll
        for (int j = 0; j < 4; ++j) acc[i][j] = (f32x4){0.f, 0.f, 0.f, 0.f};

    const int lrow = lane >> 3;
    const int lswz = ((lane & 7) ^ (lrow & 7)) << 3;

    for (int c = 0; c < 4; ++c) {
        const int k0 = c * 64;
#pragma unroll
        for (int i = 0; i < 4; ++i) {
            int r0 = w * 32 + i * 8;
            int row = r0 + lrow;
            GLOAD_LDS16(Xh + (size_t)(m0 + row) * 256 + k0 + lswz, smq + QAH + r0 * 64);
            GLOAD_LDS16(Xl + (size_t)(m0 + row) * 256 + k0 + lswz, smq + QAL + r0 * 64);
            GLOAD_LDS16(Bh + (size_t)(n0 + row) * 256 + k0 + lswz, smq + QBH + r0 * 64);
            GLOAD_LDS16(Bl + (size_t)(n0 + row) * 256 + k0 + lswz, smq + QBL + r0 * 64);
        }
        __syncthreads();
#pragma unroll
        for (int ks = 0; ks < 2; ++ks) {
            const int kg = ks * 4 + quad;
            const int rsw = (kg ^ (l15 & 7)) << 3;
            half8 ah[4], al[4], bh[4], bl[4];
#pragma unroll
            for (int i = 0; i < 4; ++i) {
                int m = wm + i * 16 + l15;
                int n = wn + i * 16 + l15;
                ah[i] = *(const half8*)(smq + QAH + m * 64 + rsw);
                al[i] = *(const half8*)(smq + QAL + m * 64 + rsw);
                bh[i] = *(const half8*)(smq + QBH + n * 64 + rsw);
                bl[i] = *(const half8*)(smq + QBL + n * 64 + rsw);
            }
#pragma unroll
            for (int mi = 0; mi < 4; ++mi)
#pragma unroll
                for (int ni = 0; ni < 4; ++ni) {
                    acc[mi][ni] = __builtin_amdgcn_mfma_f32_16x16x32_f16(ah[mi], bh[ni], acc[mi][ni], 0, 0, 0);
                    acc[mi][ni] = __builtin_amdgcn_mfma_f32_16x16x32_f16(al[mi], bh[ni], acc[mi][ni], 0, 0, 0);
                    acc[mi][ni] = __builtin_amdgcn_mfma_f32_16x16x32_f16(ah[mi], bl[ni], acc[mi][ni], 0, 0, 0);
                }
        }
        __syncthreads();
    }

    // ---- epilogue via LDS (stride 136 shorts) ----
    if (z < 2) {
#pragma unroll
        for (int mi = 0; mi < 4; ++mi)
#pragma unroll
            for (int ni = 0; ni < 4; ++ni)
#pragma unroll
                for (int r = 0; r < 4; ++r)
                    *(f16*)(smq + (wm + mi * 16 + quad * 4 + r) * 136 + wn + ni * 16 + l15) =
                        (f16)acc[mi][ni][r];
        __syncthreads();
        int cg = tid & 15;
        if (z == 1) {
#pragma unroll
            for (int j = 0; j < 8; ++j) {
                int row = j * 16 + (tid >> 4);
                half8 v = *(const half8*)(smq + row * 136 + cg * 8);
                *(half8*)&Qh[(size_t)(m0 + row) * 512 + n0 + cg * 8] = v;
            }
        } else {
            // K -> fragment-major
#pragma unroll
            for (int j = 0; j < 8; ++j) {
                int row  = j * 16 + (tid >> 4);
                int keyg = m0 + row;
                int bb2  = keyg >> 11, s = keyg & 2047;
                int d    = n0 + cg * 8;
                int t    = s >> 5, kb = (s >> 4) & 1;
                int ks   = d >> 5, qd = (d >> 3) & 3;
                int ln   = (s & 15) + 16 * qd;
                half8 v = *(const half8*)(smq + row * 136 + cg * 8);
                *(half8*)&Kf[(size_t)bb2 * 1048576 +
                             ((((size_t)t * 2 + kb) * 16 + ks) * 64 + ln) * 8] = v;
            }
        }
    } else {
        // transpose in LDS: [dv_local][key_local]
#pragma unroll
        for (int mi = 0; mi < 4; ++mi)
#pragma unroll
            for (int ni = 0; ni < 4; ++ni)
#pragma unroll
                for (int r = 0; r < 4; ++r)
                    *(f16*)(smq + (wn + ni * 16 + l15) * 136 + wm + mi * 16 + quad * 4 + r) =
                        (f16)acc[mi][ni][r];
        __syncthreads();
        int bb = m0 >> 11, kb0 = m0 & 2047;
        int cg = tid & 15;
#pragma unroll
        for (int j = 0; j < 8; ++j) {
            int dvr = j * 16 + (tid >> 4);
            int dv  = n0 + dvr;
            int key = kb0 + cg * 8;
            int t   = key >> 5;
            int nb  = dv >> 5;
            int ks  = (key >> 4) & 1;
            int lh  = (key >> 3) & 1;
            int ln  = (dv & 31) + 32 * lh;
            half8 v = *(const half8*)(smq + dvr * 136 + cg * 8);
            *(half8*)&Vf[(size_t)bb * 1048576 +
                         ((((size_t)t * 16 + nb) * 2 + ks) * 64 + ln) * 8] = v;
        }
    }
}

// ---------------------------------------------------------------------------
// Kernel 3: MFMA flash attention, fragment-direct (no K/V LDS staging).
// Scores: S^T = K·Q^T via 16x16x32 (A=K frags from GLOBAL, B=Q resident).
//   C-layout: q = lane&15 -> per-lane softmax state, 2-step shuffle trees.
// PV: 32x32x16, A=P (LDS, parity double-buffered), B=V frags from GLOBAL.
// ONE barrier per iteration. LDS = 11 KB. 2 blocks/CU (VGPR-capped).
// ---------------------------------------------------------------------------
#define PSTR 40      // P row stride in shorts (32 keys + 8 pad)
#define LPP0 0       // P parity 0: 64*40 = 2560 shorts
#define LPP1 2560
#define LAP0 5120    // alpha parity 0: 64 floats = 128 shorts
#define LAP1 5248
#define LFP0 5376    // flags parity 0: 4 ints = 8 shorts
#define LFP1 5384
#define LLQ  5392    // l[64] floats = 128 shorts
#define LTOT3 5520

__global__ __launch_bounds__(256, 2) void attn3(
    const f16* __restrict__ Qh, const f16* __restrict__ Kf,
    const f16* __restrict__ Vf, float* __restrict__ Y)
{
    __shared__ __align__(16) short sm[LTOT3];

    const int tid  = threadIdx.x;
    const int lane = tid & 63;
    const int w    = tid >> 6;
    // XCD-aware decode: all 32 q-blocks of a batch on one XCD
    const int gid  = blockIdx.x;
    const int b    = (gid & 7) + ((gid >> 8) << 3);
    const int q0   = ((gid >> 3) & 31) * 64;
    const int l15  = lane & 15;
    const int quad = lane >> 4;
    const int l31  = lane & 31;
    const int lhi  = lane >> 5;
    const int qhalf = w >> 1, dvhalf = w & 1;

    const f16* Kfb = Kf + (size_t)b * 1048576;
    const f16* Vfb = Vf + (size_t)b * 1048576;

    // ---- Q fragments (resident): wave w owns q rows q0+16w .. +15 ----
    half8 qh[16];
    {
        const half8* qhp = (const half8*)(Qh + ((size_t)b * SS + q0 + w * 16 + l15) * 512);
#pragma unroll
        for (int ks = 0; ks < 16; ++ks) qh[ks] = qhp[ks * 4 + quad];
    }

    f32x16 O[8];
#pragma unroll
    for (int n = 0; n < 8; ++n)
#pragma unroll
        for (int r = 0; r < 16; ++r) O[n][r] = 0.f;

    float m_pr = -1e30f;   // per-lane: q = l15 (replicated across quads)
    float l_r  = 0.f;

    float* ap0 = (float*)(sm + LAP0);
    float* ap1 = (float*)(sm + LAP1);
    int*   fp0 = (int*)(sm + LFP0);
    int*   fp1 = (int*)(sm + LFP1);

#pragma unroll 1
    for (int t = 0; t < 64; ++t) {
        const int par = t & 1;
        float* aptr = par ? ap1 : ap0;
        int*   fptr = par ? fp1 : fp0;
        short* pbuf = sm + (par ? LPP1 : LPP0);

        // ---- scores: S^T = K · Q^T ; A=K frags direct from global ----
        f32x4 S0 = (f32x4){0.f, 0.f, 0.f, 0.f};
        f32x4 S1 = (f32x4){0.f, 0.f, 0.f, 0.f};
        const f16* kbase = Kfb + (size_t)t * 16384 + lane * 8;
#pragma unroll
        for (int ks = 0; ks < 16; ++ks) {
            half8 k0 = *(const half8*)(kbase + ks * 512);
            half8 k1 = *(const half8*)(kbase + 8192 + ks * 512);
            S0 = __builtin_amdgcn_mfma_f32_16x16x32_f16(k0, qh[ks], S0, 0, 0, 0);
            S1 = __builtin_amdgcn_mfma_f32_16x16x32_f16(k1, qh[ks], S1, 0, 0, 0);
        }
        // S^T layout: lane q=l15, key = kb*16 + quad*4 + r

        // ---- softmax: per-lane row state, 2-step quad trees ----
        float mloc = fmaxf(fmaxf(fmaxf(S0[0], S0[1]), fmaxf(S0[2], S0[3])),
                           fmaxf(fmaxf(S1[0], S1[1]), fmaxf(S1[2], S1[3])));
        mloc = fmaxf(mloc, __shfl_xor(mloc, 16, 64));
        mloc = fmaxf(mloc, __shfl_xor(mloc, 32, 64));
        float mnew = fmaxf(m_pr, mloc);
        float al = __expf(m_pr - mnew);
        m_pr = mnew;

        float p00 = __expf(S0[0] - mnew), p01 = __expf(S0[1] - mnew);
        float p02 = __expf(S0[2] - mnew), p03 = __expf(S0[3] - mnew);
        float p10 = __expf(S1[0] - mnew), p11 = __expf(S1[1] - mnew);
        float p12 = __expf(S1[2] - mnew), p13 = __expf(S1[3] - mnew);
        float sum = ((p00 + p01) + (p02 + p03)) + ((p10 + p11) + (p12 + p13));
        sum += __shfl_xor(sum, 16, 64);
        sum += __shfl_xor(sum, 32, 64);
        l_r = l_r * al + sum;

        // ---- P write (f16x4 pairs), alpha, flag ----
        short* prow = pbuf + (w * 16 + l15) * PSTR;
        f16x4 a0, a1;
        a0.x = (f16)p00; a0.y = (f16)p01; a0.z = (f16)p02; a0.w = (f16)p03;
        a1.x = (f16)p10; a1.y = (f16)p11; a1.z = (f16)p12; a1.w = (f16)p13;
        *(f16x4*)(prow + quad * 4)      = a0;
        *(f16x4*)(prow + 16 + quad * 4) = a1;
        if (quad == 0) aptr[w * 16 + l15] = al;
        unsigned long long bm = __ballot(al < 1.f);
        if (lane == 0) fptr[w] = (bm != 0ULL) ? 1 : 0;

        __syncthreads();   // P(t)/alpha(t) visible; parity dbuf protects P(t-1) readers

        // ---- O rescale (skipped when running max unchanged) ----
        if (fptr[2 * qhalf] | fptr[2 * qhalf + 1]) {
            float av[16];
#pragma unroll
            for (int r = 0; r < 16; ++r) {
                int row = (r & 3) + ((r >> 2) << 3) + (lhi << 2);
                av[r] = aptr[qhalf * 32 + row];
            }
#pragma unroll
            for (int n = 0; n < 8; ++n)
#pragma unroll
                for (int r = 0; r < 16; ++r) O[n][r] *= av[r];
        }

        // ---- PV: O += P·V (32x32x16); B=V frags direct from global ----
        const short* pb = pbuf + (qhalf * 32 + l31) * PSTR + lhi * 8;
        half8 pA0 = *(const half8*)(pb);
        half8 pA1 = *(const half8*)(pb + 16);
        const f16* vbase = Vfb + (size_t)t * 16384 + dvhalf * 8192 + lane * 8;
#pragma unroll
        for (int n = 0; n < 8; ++n) {
            half8 v0 = *(const half8*)(vbase + n * 1024);
            half8 v1 = *(const half8*)(vbase + n * 1024 + 512);
            O[n] = __builtin_amdgcn_mfma_f32_32x32x16_f16(pA0, v0, O[n], 0, 0, 0);
            O[n] = __builtin_amdgcn_mfma_f32_32x32x16_f16(pA1, v1, O[n], 0, 0, 0);
        }
    }

    // ---- epilogue: O /= l, store ----
    float* lq = (float*)(sm + LLQ);
    if (quad == 0) lq[w * 16 + l15] = l_r;
    __syncthreads();
    float linv[16];
#pragma unroll
    for (int r = 0; r < 16; ++r) {
        int row = (r & 3) + ((r >> 2) << 3) + (lhi << 2);
        linv[r] = 1.0f / lq[qhalf * 32 + row];
    }
#pragma unroll
    for (int n = 0; n < 8; ++n) {
#pragma unroll
        for (int r = 0; r < 16; ++r) {
            int row = (r & 3) + ((r >> 2) << 3) + (lhi << 2);
            Y[((size_t)(b * SS + q0 + qhalf * 32 + row)) * 512 + dvhalf * 256 + n * 32 + l31] =
                O[n][r] * linv[r];
        }
    }
}

// ---------------------------------------------------------------------------
// Host launcher
// Workspace (f16 units): Wth(393216) Wtl(393216) Xh(8.39M) Xl(8.39M)
//                        Qh(16.78M) Kf(16.78M) Vf(16.78M)  ~136 MB
// ---------------------------------------------------------------------------
extern "C" void kernel_launch(void* const* d_in, const int* in_sizes, int n_in,
                              void* d_out, int out_size, void* d_ws, size_t ws_size,
                              hipStream_t stream)
{
    const float* x  = (const float*)d_in[0];
    const float* We = (const float*)d_in[1];
    const float* Wk = (const float*)d_in[2];
    const float* Wq = (const float*)d_in[3];
    const float* Wv = (const float*)d_in[4];
    float* out = (float*)d_out;

    const size_t WSZ = 3 * 256 * 512;          // 393216
    const size_t XSZ = (size_t)BB * SS * DIN;  // 8388608
    const size_t MSZ = (size_t)BB * SS * 512;  // 16777216

    f16* Wth = (f16*)d_ws;
    f16* Wtl = Wth + WSZ;
    f16* Xh  = Wtl + WSZ;
    f16* Xl  = Xh + XSZ;
    f16* Qh  = Xl + XSZ;
    f16* Kf  = Qh + MSZ;
    f16* Vf  = Kf + MSZ;

    prep_x<<<dim3(XSZ / 4 / 256), dim3(256), 0, stream>>>(x, Xh, Xl);

    fuse_weights<<<dim3(1536), dim3(256), 0, stream>>>(We, Wk, Wq, Wv, Wth, Wtl);

    qkv_gemm<<<dim3(4, 256, 3), dim3(256), 0, stream>>>(
        Xh, Xl, Wth, Wtl, Kf, Qh, Vf);

    attn3<<<dim3(512), dim3(256), 0, stream>>>(Qh, Kf, Vf, out);
}